// Round 1
// baseline (702.924 us; speedup 1.0000x reference)
//
#include <hip/hip_runtime.h>

// GradientConsistencyLoss on f[2,3,192,192,192] fp32.
// loss = 0.1 * ( mean(div^2) + mean(sqrt(cx^2+cy^2+cz^2+1e-8)) )
// jnp.gradient semantics: central interior, one-sided edges, unit spacing.
//
// R9: LDS halo-sharing on top of R8's row-pair register tiling.
// Evidence: timed 234us = 2x ~97us harness poison fills + gcl(~35us) + reduce.
// gcl issued 24 B/voxel (12 float3 loads / 6 voxels); the hm/hp halo loads of
// interior waves duplicate neighbor waves' cur rows AT THE SAME DEPTH in the
// SAME BLOCK. So: each step every wave publishes its cur row-pair to a
// double-buffered LDS plane (9 floats/lane packed into a 12-float padded slot
// -> 2x ds_write_b128 + b32, stride 48B = conflict-free), one sync per step,
// interior waves read h-halos from LDS. Only wave 0 / wave 3 keep one global
// edge-halo row each. Global row-loads per block-step-channel: 16 -> 10
// (24 -> 15 B/voxel). LDS values are bit-copies of regs -> result bit-exact.
// Double-buffer hazard: read_s(buf p) and write_{s+2}(buf p) are separated by
// sync_{s+1}; write_{s+1} targets buf p^1. One barrier per step suffices.

#define DEP 192
#define HGT 192
#define WID 192
#define NB  2

constexpr int SD = HGT * WID;             // d-stride (floats)
constexpr int SC = DEP * SD;              // channel stride
constexpr int SB = 3 * SC;                // batch stride
constexpr int DSEG = 12;                  // planes per thread
constexpr int NSEG = DEP / DSEG;          // 16
constexpr int RPB  = 4;                   // row-pairs per block (= waves)
constexpr int NRPG = (HGT / 2) / RPB;     // 24 row-pair groups
constexpr int NBLK = NB * NSEG * NRPG;    // 768 blocks = 3/CU exactly
constexpr float SCALE = (float)(0.1 / (double)((long long)NB * DEP * HGT * WID));
constexpr float EPS_C = 1e-8f;

struct V3 { float x, y, z; };
__device__ __forceinline__ V3 ld3(const float* p) {
    const float3 t = *(const float3*)p;     // 12B load -> global_load_dwordx3
    V3 r; r.x = t.x; r.y = t.y; r.z = t.z; return r;
}

// pack 3 channels (9 floats) of one row into a 12-float padded LDS slot
__device__ __forceinline__ void pack9(float* q, const V3 a0, const V3 a1, const V3 a2) {
    ((float4*)q)[0] = make_float4(a0.x, a0.y, a0.z, a1.x);
    ((float4*)q)[1] = make_float4(a1.y, a1.z, a2.x, a2.y);
    q[8] = a2.z;
}
__device__ __forceinline__ void unpack9(const float* q, V3 v[3]) {
    const float4 a = ((const float4*)q)[0];
    const float4 b = ((const float4*)q)[1];
    const float  c = q[8];
    v[0] = {a.x, a.y, a.z};
    v[1] = {a.w, b.x, b.y};
    v[2] = {b.z, b.w, c};
}

__global__ __launch_bounds__(256, 3) void gcl_kernel(const float* __restrict__ f,
                                                     float* __restrict__ ws) {
    const int tid  = threadIdx.x;
    const int lane = tid & 63;
    const int wv   = tid >> 6;

    int bid = blockIdx.x;
    const int rpg = bid % NRPG; bid /= NRPG;
    const int dsg = bid % NSEG;
    const int b   = bid / NSEG;

    const int h0 = (rpg * RPB + wv) * 2;      // even row of the pair
    const int h1 = h0 + 1;
    const int w  = lane * 3;
    const int d0 = dsg * DSEG;

    const int hmrow = (h0 > 0) ? h0 - 1 : 0;           // used by wave 0 only
    const int hprow = (h1 < HGT - 1) ? h1 + 1 : HGT - 1; // used by wave 3 only
    const float sy0 = (h0 == 0) ? 1.f : 0.5f;
    const float sy1 = (h1 == HGT - 1) ? 1.f : 0.5f;
    const float s0w = (lane == 0) ? 1.f : 0.5f;   // w==0 true edge
    const float s2w = (lane == 63) ? 1.f : 0.5f;  // w+2==191 true edge

    const float* base = f + b * SB + w;
    const int r0 = h0 * WID, r1 = h1 * WID, rm = hmrow * WID, rp = hprow * WID;

    // double-buffered per-depth row planes: [buf][blockrow][lane][12-float slot]
    __shared__ float sh[2][2 * RPB][64][12];   // 48 KB -> 3 blocks/CU fits 160KB

    // rolling d-pipeline (all wave-uniform control)
    V3 prev[3][2], cur[3][2], nxt[3][2];
    V3 hm[3] = {}, hp[3] = {};
    const int pm = (d0 > 0) ? d0 - 1 : 0;
#pragma unroll
    for (int c = 0; c < 3; ++c) {
        const float* pc = base + c * SC;
        prev[c][0] = ld3(pc + pm * SD + r0);
        prev[c][1] = ld3(pc + pm * SD + r1);
        cur[c][0]  = ld3(pc + d0 * SD + r0);
        cur[c][1]  = ld3(pc + d0 * SD + r1);
        nxt[c][0]  = ld3(pc + (d0 + 1) * SD + r0);   // d0+1 <= 181
        nxt[c][1]  = ld3(pc + (d0 + 1) * SD + r1);
    }
    if (wv == 0) {
#pragma unroll
        for (int c = 0; c < 3; ++c) hm[c] = ld3(base + c * SC + d0 * SD + rm);
    }
    if (wv == RPB - 1) {
#pragma unroll
        for (int c = 0; c < 3; ++c) hp[c] = ld3(base + c * SC + d0 * SD + rp);
    }

    float local = 0.f;

#pragma unroll
    for (int s = 0; s < DSEG; ++s) {
        const int d = d0 + s;
        const int p = s & 1;

        // ---- publish cur (depth d) row-pair to LDS ----
        pack9(&sh[p][2 * wv + 0][lane][0], cur[0][0], cur[1][0], cur[2][0]);
        pack9(&sh[p][2 * wv + 1][lane][0], cur[0][1], cur[1][1], cur[2][1]);

        // ---- prefetch everything for step s+1 (one full iteration early) ----
        V3 nn[3][2], nhm[3], nhp[3];
        if (s < DSEG - 1) {
            const int dn = d + 1;
            const int d2 = (d + 2 < DEP) ? d + 2 : DEP - 1;  // clamp == edge rule
#pragma unroll
            for (int c = 0; c < 3; ++c) {
                const float* pc = base + c * SC;
                nn[c][0] = ld3(pc + d2 * SD + r0);
                nn[c][1] = ld3(pc + d2 * SD + r1);
            }
            if (wv == 0) {
#pragma unroll
                for (int c = 0; c < 3; ++c) nhm[c] = ld3(base + c * SC + dn * SD + rm);
            }
            if (wv == RPB - 1) {
#pragma unroll
                for (int c = 0; c < 3; ++c) nhp[c] = ld3(base + c * SC + dn * SD + rp);
            }
        }

        __syncthreads();   // LDS plane p (depth d) visible to all waves

        const float sx = (d == 0 || d == DEP - 1) ? 1.f : 0.5f;

#pragma unroll
        for (int r = 0; r < 2; ++r) {
            const float syr = r ? sy1 : sy0;
            V3 lo3[3], hi3[3];
            if (r == 0) {
                if (wv == 0) { lo3[0] = hm[0]; lo3[1] = hm[1]; lo3[2] = hm[2]; }
                else         unpack9(&sh[p][2 * wv - 1][lane][0], lo3);
                hi3[0] = cur[0][1]; hi3[1] = cur[1][1]; hi3[2] = cur[2][1];
            } else {
                lo3[0] = cur[0][0]; lo3[1] = cur[1][0]; lo3[2] = cur[2][0];
                if (wv == RPB - 1) { hi3[0] = hp[0]; hi3[1] = hp[1]; hi3[2] = hp[2]; }
                else               unpack9(&sh[p][2 * wv + 2][lane][0], hi3);
            }

            float gx[3][3], gy[3][3], gz[3][3];
#pragma unroll
            for (int c = 0; c < 3; ++c) {
                // d-gradient from pipeline registers
                gx[c][0] = sx * (nxt[c][r].x - prev[c][r].x);
                gx[c][1] = sx * (nxt[c][r].y - prev[c][r].y);
                gx[c][2] = sx * (nxt[c][r].z - prev[c][r].z);
                // h-gradient: halo from LDS (interior) or edge regs
                gy[c][0] = syr * (hi3[c].x - lo3[c].x);
                gy[c][1] = syr * (hi3[c].y - lo3[c].y);
                gy[c][2] = syr * (hi3[c].z - lo3[c].z);
                // w-gradient: cross-lane shuffles, true edges at lane 0/63
                float lv = __shfl_up(cur[c][r].z, 1, 64);
                float rv = __shfl_down(cur[c][r].x, 1, 64);
                if (lane == 0)  lv = cur[c][r].x;
                if (lane == 63) rv = cur[c][r].z;
                gz[c][0] = s0w * (cur[c][r].y - lv);
                gz[c][1] = 0.5f * (cur[c][r].z - cur[c][r].x);
                gz[c][2] = s2w * (rv - cur[c][r].y);
            }
#pragma unroll
            for (int j = 0; j < 3; ++j) {
                const float dv = gx[0][j] + gy[1][j] + gz[2][j];
                const float cx = gz[1][j] - gy[2][j];
                const float cy = gx[2][j] - gz[0][j];
                const float cz = gy[0][j] - gx[1][j];
                local += dv * dv +
                         __builtin_amdgcn_sqrtf(cx * cx + cy * cy + cz * cz + EPS_C);
            }
        }

        // ---- rotate pipeline (uniform control) ----
        if (s < DSEG - 1) {
#pragma unroll
            for (int c = 0; c < 3; ++c) {
                prev[c][0] = cur[c][0]; prev[c][1] = cur[c][1];
                cur[c][0]  = nxt[c][0]; cur[c][1]  = nxt[c][1];
                nxt[c][0]  = nn[c][0];  nxt[c][1]  = nn[c][1];
            }
            if (wv == 0) {
#pragma unroll
                for (int c = 0; c < 3; ++c) hm[c] = nhm[c];
            }
            if (wv == RPB - 1) {
#pragma unroll
                for (int c = 0; c < 3; ++c) hp[c] = nhp[c];
            }
        }
    }

    // ---- wave64 butterfly -> cross-wave LDS -> one store per block ----
#pragma unroll
    for (int off = 32; off > 0; off >>= 1)
        local += __shfl_down(local, off, 64);

    __shared__ float wsum[4];
    if (lane == 0) wsum[wv] = local;
    __syncthreads();
    if (tid == 0)
        ws[blockIdx.x] = wsum[0] + wsum[1] + wsum[2] + wsum[3];
}

__global__ __launch_bounds__(256) void gcl_reduce(const float* __restrict__ ws,
                                                  float* __restrict__ out) {
    float s = 0.f;
    for (int i = threadIdx.x; i < NBLK; i += 256) s += ws[i];
#pragma unroll
    for (int off = 32; off > 0; off >>= 1)
        s += __shfl_down(s, off, 64);
    __shared__ float wsum[4];
    const int lane = threadIdx.x & 63;
    const int wv   = threadIdx.x >> 6;
    if (lane == 0) wsum[wv] = s;
    __syncthreads();
    if (threadIdx.x == 0)
        out[0] = (wsum[0] + wsum[1] + wsum[2] + wsum[3]) * SCALE;
}

extern "C" void kernel_launch(void* const* d_in, const int* in_sizes, int n_in,
                              void* d_out, int out_size, void* d_ws, size_t ws_size,
                              hipStream_t stream) {
    const float* f = (const float*)d_in[0];
    float* out = (float*)d_out;
    float* ws  = (float*)d_ws;   // NBLK*4 = 3 KB scratch
    gcl_kernel<<<dim3(NBLK), dim3(256), 0, stream>>>(f, ws);
    gcl_reduce<<<dim3(1), dim3(256), 0, stream>>>(ws, out);
}

// Round 2
// 235.605 us; speedup vs baseline: 2.9835x; 2.9835x over previous
//
#include <hip/hip_runtime.h>

// GradientConsistencyLoss on f[2,3,192,192,192] fp32.
// loss = 0.1 * ( mean(div^2) + mean(sqrt(cx^2+cy^2+cz^2+1e-8)) )
// jnp.gradient semantics: central interior, one-sided edges, unit spacing.
//
// R10: row-TRIPLE register tiling (no LDS - R4/R7/R9 all proved hipcc demotes
// the register pipeline to scratch when __shared__ staging coexists: R9 showed
// VGPR 84 + 823MB WRITE_SIZE = scratch round-trip, 6x regression).
// Wave owns rows (h, h+1, h+2): middle row's h-neighbors are in-register, so
// halo loads amortize over 3 rows instead of 2.
//   per step per lane: 9 row loads (pipeline feed) + 2 halo loads = 15 float3
//   = 180 B / 9 voxels = 20 B/voxel   (R8: 12 float3 / 6 voxels = 24 B/voxel)
// State = 144 floats > 168-VGPR cap @3 waves/SIMD -> __launch_bounds__(256,2)
// (cap 256, no spill). Grid 2*16*16 = 512 blocks = exactly 2 blocks/CU.
// d-march with the proven 1-iter-ahead prefetch (nn/nhm/nhp); w-neighbors via
// __shfl (lane 0/63 true edges); all loop-carried state wave-uniform control.

#define DEP 192
#define HGT 192
#define WID 192
#define NB  2

constexpr int SD = HGT * WID;             // d-stride (floats)
constexpr int SC = DEP * SD;              // channel stride
constexpr int SB = 3 * SC;                // batch stride
constexpr int DSEG = 12;                  // planes per thread
constexpr int NSEG = DEP / DSEG;          // 16
constexpr int RWS  = 3;                   // rows per wave
constexpr int RPB  = 4;                   // waves per block
constexpr int ROWB = RWS * RPB;           // 12 rows per block
constexpr int NRPG = HGT / ROWB;          // 16 row groups
constexpr int NBLK = NB * NSEG * NRPG;    // 512 blocks = 2/CU exactly
constexpr float SCALE = (float)(0.1 / (double)((long long)NB * DEP * HGT * WID));
constexpr float EPS_C = 1e-8f;

struct V3 { float x, y, z; };
__device__ __forceinline__ V3 ld3(const float* p) {
    const float3 t = *(const float3*)p;     // 12B load -> global_load_dwordx3
    V3 r; r.x = t.x; r.y = t.y; r.z = t.z; return r;
}

__global__ __launch_bounds__(256, 2) void gcl_kernel(const float* __restrict__ f,
                                                     float* __restrict__ ws) {
    const int tid  = threadIdx.x;
    const int lane = tid & 63;
    const int wv   = tid >> 6;

    int bid = blockIdx.x;
    const int rpg = bid % NRPG; bid /= NRPG;
    const int dsg = bid % NSEG;
    const int b   = bid / NSEG;

    const int h0 = (rpg * RPB + wv) * RWS;    // first of 3 owned rows
    const int w  = lane * 3;
    const int d0 = dsg * DSEG;

    const int hmrow = (h0 > 0) ? h0 - 1 : 0;                    // below halo
    const int hprow = (h0 + RWS < HGT) ? h0 + RWS : HGT - 1;    // above halo
    const float s0w = (lane == 0) ? 1.f : 0.5f;   // w==0 true edge
    const float s2w = (lane == 63) ? 1.f : 0.5f;  // w+2==191 true edge

    const float* base = f + b * SB + w;
    const int rr0 = (h0 + 0) * WID;
    const int rr1 = (h0 + 1) * WID;
    const int rr2 = (h0 + 2) * WID;
    const int rm  = hmrow * WID, rp = hprow * WID;

    // rolling d-pipeline (all wave-uniform control)
    V3 prev[3][RWS], cur[3][RWS], nxt[3][RWS], hm[3], hp[3];
    const int pm = (d0 > 0) ? d0 - 1 : 0;
#pragma unroll
    for (int c = 0; c < 3; ++c) {
        const float* pc = base + c * SC;
        prev[c][0] = ld3(pc + pm * SD + rr0);
        prev[c][1] = ld3(pc + pm * SD + rr1);
        prev[c][2] = ld3(pc + pm * SD + rr2);
        cur[c][0]  = ld3(pc + d0 * SD + rr0);
        cur[c][1]  = ld3(pc + d0 * SD + rr1);
        cur[c][2]  = ld3(pc + d0 * SD + rr2);
        nxt[c][0]  = ld3(pc + (d0 + 1) * SD + rr0);   // d0+1 <= 181
        nxt[c][1]  = ld3(pc + (d0 + 1) * SD + rr1);
        nxt[c][2]  = ld3(pc + (d0 + 1) * SD + rr2);
        hm[c]      = ld3(pc + d0 * SD + rm);
        hp[c]      = ld3(pc + d0 * SD + rp);
    }

    float local = 0.f;

#pragma unroll
    for (int s = 0; s < DSEG; ++s) {
        const int d = d0 + s;

        // ---- prefetch everything for step s+1 (one full iteration early) ----
        V3 nn[3][RWS], nhm[3], nhp[3];
        if (s < DSEG - 1) {
            const int dn = d + 1;
            const int d2 = (d + 2 < DEP) ? d + 2 : DEP - 1;  // clamp == edge rule
#pragma unroll
            for (int c = 0; c < 3; ++c) {
                const float* pc = base + c * SC;
                nn[c][0] = ld3(pc + d2 * SD + rr0);
                nn[c][1] = ld3(pc + d2 * SD + rr1);
                nn[c][2] = ld3(pc + d2 * SD + rr2);
                nhm[c]   = ld3(pc + dn * SD + rm);
                nhp[c]   = ld3(pc + dn * SD + rp);
            }
        }

        const float sx = (d == 0 || d == DEP - 1) ? 1.f : 0.5f;

#pragma unroll
        for (int r = 0; r < RWS; ++r) {
            const int h = h0 + r;
            const float syr = (h == 0 || h == HGT - 1) ? 1.f : 0.5f;
            float gx[3][3], gy[3][3], gz[3][3];
#pragma unroll
            for (int c = 0; c < 3; ++c) {
                // d-gradient from pipeline registers
                gx[c][0] = sx * (nxt[c][r].x - prev[c][r].x);
                gx[c][1] = sx * (nxt[c][r].y - prev[c][r].y);
                gx[c][2] = sx * (nxt[c][r].z - prev[c][r].z);
                // h-gradient: neighbors in-register for middle row; halo regs
                // for the outer rows (static selection, r is compile-time)
                const V3 lo = (r == 0)       ? hm[c] : cur[c][r - 1 < 0 ? 0 : r - 1];
                const V3 hi = (r == RWS - 1) ? hp[c] : cur[c][r + 1 >= RWS ? RWS - 1 : r + 1];
                gy[c][0] = syr * (hi.x - lo.x);
                gy[c][1] = syr * (hi.y - lo.y);
                gy[c][2] = syr * (hi.z - lo.z);
                // w-gradient: cross-lane shuffles, true edges at lane 0/63
                float lv = __shfl_up(cur[c][r].z, 1, 64);
                float rv = __shfl_down(cur[c][r].x, 1, 64);
                if (lane == 0)  lv = cur[c][r].x;
                if (lane == 63) rv = cur[c][r].z;
                gz[c][0] = s0w * (cur[c][r].y - lv);
                gz[c][1] = 0.5f * (cur[c][r].z - cur[c][r].x);
                gz[c][2] = s2w * (rv - cur[c][r].y);
            }
#pragma unroll
            for (int j = 0; j < 3; ++j) {
                const float dv = gx[0][j] + gy[1][j] + gz[2][j];
                const float cx = gz[1][j] - gy[2][j];
                const float cy = gx[2][j] - gz[0][j];
                const float cz = gy[0][j] - gx[1][j];
                local += dv * dv +
                         __builtin_amdgcn_sqrtf(cx * cx + cy * cy + cz * cz + EPS_C);
            }
        }

        // ---- rotate pipeline (uniform control) ----
        if (s < DSEG - 1) {
#pragma unroll
            for (int c = 0; c < 3; ++c) {
#pragma unroll
                for (int r = 0; r < RWS; ++r) {
                    prev[c][r] = cur[c][r];
                    cur[c][r]  = nxt[c][r];
                    nxt[c][r]  = nn[c][r];
                }
                hm[c] = nhm[c]; hp[c] = nhp[c];
            }
        }
    }

    // ---- wave64 butterfly -> cross-wave LDS -> one store per block ----
#pragma unroll
    for (int off = 32; off > 0; off >>= 1)
        local += __shfl_down(local, off, 64);

    __shared__ float wsum[4];
    if (lane == 0) wsum[wv] = local;
    __syncthreads();
    if (tid == 0)
        ws[blockIdx.x] = wsum[0] + wsum[1] + wsum[2] + wsum[3];
}

__global__ __launch_bounds__(256) void gcl_reduce(const float* __restrict__ ws,
                                                  float* __restrict__ out) {
    float s = 0.f;
    for (int i = threadIdx.x; i < NBLK; i += 256) s += ws[i];
#pragma unroll
    for (int off = 32; off > 0; off >>= 1)
        s += __shfl_down(s, off, 64);
    __shared__ float wsum[4];
    const int lane = threadIdx.x & 63;
    const int wv   = threadIdx.x >> 6;
    if (lane == 0) wsum[wv] = s;
    __syncthreads();
    if (threadIdx.x == 0)
        out[0] = (wsum[0] + wsum[1] + wsum[2] + wsum[3]) * SCALE;
}

extern "C" void kernel_launch(void* const* d_in, const int* in_sizes, int n_in,
                              void* d_out, int out_size, void* d_ws, size_t ws_size,
                              hipStream_t stream) {
    const float* f = (const float*)d_in[0];
    float* out = (float*)d_out;
    float* ws  = (float*)d_ws;   // NBLK*4 = 2 KB scratch
    gcl_kernel<<<dim3(NBLK), dim3(256), 0, stream>>>(f, ws);
    gcl_reduce<<<dim3(1), dim3(256), 0, stream>>>(ws, out);
}